// Round 4
// baseline (1285.144 us; speedup 1.0000x reference)
//
#include <hip/hip_runtime.h>

#define NN 100000
#define NE 3200000
#define ET (NE + NN)
#define NEG_SLOPE 0.2f
#define SCAN_B 256
#define BSHIFT 6
#define NBUC ((NN + (1 << BSHIFT) - 1) >> BSHIFT)   // 1563 buckets of 64 nodes

__device__ __forceinline__ float lrelu(float v) { return v > 0.f ? v : NEG_SLOPE * v; }

__global__ void fill_int_kernel(int* __restrict__ p, int v, int n) {
    int i = blockIdx.x * blockDim.x + threadIdx.x;
    int stride = gridDim.x * blockDim.x;
    for (; i < n; i += stride) p[i] = v;
}

// ---------------- CSR build ----------------

__global__ void count_kernel(const int* __restrict__ dst, int* __restrict__ deg) {
    int idx = blockIdx.x * blockDim.x + threadIdx.x;
    if (idx >= ET) return;
    int d = (idx < NE) ? dst[idx] : idx - NE;   // self loops appended
    atomicAdd(&deg[d], 1);
}

__global__ void scan_local_kernel(const int* __restrict__ deg, int* __restrict__ rowptr,
                                  int* __restrict__ bsum, int N) {
    __shared__ int tmp[SCAN_B];
    int i = blockIdx.x * SCAN_B + threadIdx.x;
    int v = (i < N) ? deg[i] : 0;
    tmp[threadIdx.x] = v;
    __syncthreads();
    for (int off = 1; off < SCAN_B; off <<= 1) {
        int t = (threadIdx.x >= off) ? tmp[threadIdx.x - off] : 0;
        __syncthreads();
        tmp[threadIdx.x] += t;
        __syncthreads();
    }
    if (i < N) rowptr[i] = tmp[threadIdx.x] - v;
    if (threadIdx.x == SCAN_B - 1) bsum[blockIdx.x] = tmp[SCAN_B - 1];
}

__global__ void scan_bsum_kernel(int* __restrict__ bsum, int nb) {
    __shared__ int tmp[1024];
    int v = (threadIdx.x < nb) ? bsum[threadIdx.x] : 0;
    tmp[threadIdx.x] = v;
    __syncthreads();
    for (int off = 1; off < 1024; off <<= 1) {
        int t = (threadIdx.x >= off) ? tmp[threadIdx.x - off] : 0;
        __syncthreads();
        tmp[threadIdx.x] += t;
        __syncthreads();
    }
    if (threadIdx.x < nb) bsum[threadIdx.x] = tmp[threadIdx.x] - v;
}

// rowptr finalize + woff copy + bucket bases (boff[b] = rowptr[b<<BSHIFT])
__global__ void scan_add_kernel(int* __restrict__ rowptr, const int* __restrict__ bsum,
                                int* __restrict__ woff, int* __restrict__ boff, int N) {
    int i = blockIdx.x * blockDim.x + threadIdx.x;
    if (i < N) {
        int r = rowptr[i] + bsum[i / SCAN_B];
        rowptr[i] = r;
        woff[i] = r;
        if ((i & ((1 << BSHIFT) - 1)) == 0) boff[i >> BSHIFT] = r;
    }
    if (i == 0) rowptr[N] = ET;
}

// phase 1: coarse scatter into dst-buckets. Positions within a bucket are
// allocated densely in time -> 8B stores fill lines quickly (write combining).
__global__ void p1_kernel(const int* __restrict__ src, const int* __restrict__ dst,
                          int* __restrict__ boff, uint2* __restrict__ tmp) {
    int idx = blockIdx.x * blockDim.x + threadIdx.x;
    if (idx >= ET) return;
    int s, d;
    if (idx < NE) { s = src[idx]; d = dst[idx]; }
    else { s = d = idx - NE; }
    int p = atomicAdd(&boff[d >> BSHIFT], 1);
    tmp[p] = make_uint2((unsigned)s, (unsigned)d);
}

// phase 2: fine scatter, one block per bucket. Destination working set per
// block = 64 nodes * ~33 edges * 4B ~= 8.4KB -> stays in one XCD's L1/L2,
// lines fill completely before writeback.
__global__ __launch_bounds__(256) void p2_kernel(const int* __restrict__ rowptr,
                                                 const uint2* __restrict__ tmp,
                                                 int* __restrict__ woff,
                                                 int* __restrict__ ssrc) {
    int b = blockIdx.x;
    int nlo = b << BSHIFT;
    int nhi = nlo + (1 << BSHIFT); if (nhi > NN) nhi = NN;
    int lo = rowptr[nlo], hi = rowptr[nhi];
    for (int k = lo + threadIdx.x; k < hi; k += blockDim.x) {
        uint2 e = tmp[k];
        int p = atomicAdd(&woff[e.y], 1);
        ssrc[p] = (int)e.x;
    }
}

// ---------------- dense per-layer kernels ----------------

template <int FIN, int FOUT>
__global__ void gemm_kernel(const float* __restrict__ x, const float* __restrict__ W,
                            float* __restrict__ h, int N) {
    __shared__ float Ws[FIN * FOUT];
    for (int i = threadIdx.x; i < FIN * FOUT; i += blockDim.x) Ws[i] = W[i];
    __syncthreads();
    int idx = blockIdx.x * blockDim.x + threadIdx.x;
    if (idx >= N * FOUT) return;
    int n = idx / FOUT, f = idx - n * FOUT;
    const float* xr = x + (long)n * FIN;
    float a = 0.f;
#pragma unroll 8
    for (int k = 0; k < FIN; ++k) a += xr[k] * Ws[k * FOUT + f];
    h[idx] = a;
}

template <int H, int C>
__global__ void attn_kernel(const float* __restrict__ h, const float* __restrict__ a_src,
                            const float* __restrict__ a_dst, float* __restrict__ esrc,
                            float* __restrict__ edst, int N) {
    int idx = blockIdx.x * blockDim.x + threadIdx.x;
    if (idx >= N * H) return;
    int hh = idx % H;
    const float* hp = h + (long)idx * C;
    float s = 0.f, d = 0.f;
#pragma unroll
    for (int c = 0; c < C; ++c) {
        float v = hp[c];
        s += v * a_src[hh * C + c];
        d += v * a_dst[hh * C + c];
    }
    esrc[idx] = s;
    edst[idx] = d;
}

// ---------------- CSR gather aggregation, single-pass softmax ----------------
template <int H, int C, int L, int G, int NPW, bool ELU>
__global__ __launch_bounds__(256) void agg_kernel(
    const int* __restrict__ rowptr, const int* __restrict__ ssrc,
    const float* __restrict__ esrc, const float* __restrict__ edst,
    const float* __restrict__ hbuf, const float* __restrict__ b,
    float* __restrict__ out, int N) {
    constexpr int F = H * C;
    constexpr int AQ = F / 4;
    constexpr int S = L * G;
    static_assert(S * NPW == 64, "wave layout");
    int lane = threadIdx.x & 63;
    int wave = threadIdx.x >> 6;
    int sub = lane / S;
    int ls = lane - sub * S;
    int g = ls / L, q = ls - g * L;
    int n = (blockIdx.x * 4 + wave) * NPW + sub;
    if (n >= N) return;
    int h = (q < AQ) ? (4 * q) / C : 0;
    int qa = (q < AQ) ? q : 0;
    float edn = edst[n * H + h];
    int beg = rowptr[n], end = rowptr[n + 1];
    const float4* hb4 = (const float4*)hbuf;
    float sum = 0.f;
    float4 acc = make_float4(0.f, 0.f, 0.f, 0.f);
    for (int k = beg + g; k < end; k += G) {
        int s = ssrc[k];
        float e = lrelu(esrc[s * H + h] + edn);
        float ex = (q < AQ) ? __expf(e) : 0.f;
        float4 hv = hb4[(long)s * AQ + qa];
        acc.x += ex * hv.x;
        acc.y += ex * hv.y;
        acc.z += ex * hv.z;
        acc.w += ex * hv.w;
        sum += ex;
    }
#pragma unroll
    for (int step = L; step < S; step <<= 1) {
        sum += __shfl_xor(sum, step);
        acc.x += __shfl_xor(acc.x, step);
        acc.y += __shfl_xor(acc.y, step);
        acc.z += __shfl_xor(acc.z, step);
        acc.w += __shfl_xor(acc.w, step);
    }
    if (g == 0 && q < AQ) {
        float4 bb = ((const float4*)b)[q];
        float inv = 1.f / (sum + 1e-16f);
        float4 v;
        v.x = acc.x * inv + bb.x;
        v.y = acc.y * inv + bb.y;
        v.z = acc.z * inv + bb.z;
        v.w = acc.w * inv + bb.w;
        if (ELU) {
            v.x = v.x > 0.f ? v.x : __expf(v.x) - 1.f;
            v.y = v.y > 0.f ? v.y : __expf(v.y) - 1.f;
            v.z = v.z > 0.f ? v.z : __expf(v.z) - 1.f;
            v.w = v.w > 0.f ? v.w : __expf(v.w) - 1.f;
        }
        ((float4*)(out + (long)n * F))[q] = v;
    }
}

static inline int cdiv(long a, int b) { return (int)((a + b - 1) / b); }

extern "C" void kernel_launch(void* const* d_in, const int* in_sizes, int n_in,
                              void* d_out, int out_size, void* d_ws, size_t ws_size,
                              hipStream_t stream) {
    const float* x1 = (const float*)d_in[0];
    const int* ei = (const int*)d_in[1];
    const int* src = ei;
    const int* dst = ei + NE;
    const float* W1 = (const float*)d_in[2];
    const float* as1 = (const float*)d_in[3];
    const float* ad1 = (const float*)d_in[4];
    const float* b1 = (const float*)d_in[5];
    const float* W2 = (const float*)d_in[6];
    const float* as2 = (const float*)d_in[7];
    const float* ad2 = (const float*)d_in[8];
    const float* b2 = (const float*)d_in[9];
    const float* W3 = (const float*)d_in[10];
    const float* as3 = (const float*)d_in[11];
    const float* ad3 = (const float*)d_in[12];
    const float* b3 = (const float*)d_in[13];
    float* out = (float*)d_out;

    // workspace carve (~79 MB; round-1 proved >= 96 MB available)
    char* wsb = (char*)d_ws;
    float* hbuf = (float*)wsb;              wsb += (long)NN * 64 * 4;
    float* x2 = (float*)wsb;                wsb += (long)NN * 16 * 4;
    // union region: tmp (CSR build only) aliases x3 (layers 2-3 only)
    char* unionreg = wsb;                   wsb += (long)ET * 8;  // 26.4MB >= NN*64*4
    uint2* tmp = (uint2*)unionreg;
    float* x3 = (float*)unionreg;
    float* esrc = (float*)wsb;              wsb += (long)NN * 8 * 4;
    float* edst = (float*)wsb;              wsb += (long)NN * 8 * 4;
    int* ssrc = (int*)wsb;                  wsb += (long)ET * 4;
    int* rowptr = (int*)wsb;                wsb += (long)(NN + 1) * 4;
    int* woff = (int*)wsb;                  wsb += (long)NN * 4;
    int* deg = (int*)wsb;                   wsb += (long)NN * 4;
    int* bsum = (int*)wsb;                  wsb += 1024 * 4;
    int* boff = (int*)wsb;                  wsb += (long)(NBUC + 1) * 4;

    const int B = 256;
    const int nScanBlocks = cdiv(NN, SCAN_B);

    // ---- CSR build (once, reused by all 3 layers) ----
    fill_int_kernel<<<512, B, 0, stream>>>(deg, 0, NN);
    count_kernel<<<cdiv(ET, B), B, 0, stream>>>(dst, deg);
    scan_local_kernel<<<nScanBlocks, SCAN_B, 0, stream>>>(deg, rowptr, bsum, NN);
    scan_bsum_kernel<<<1, 1024, 0, stream>>>(bsum, nScanBlocks);
    scan_add_kernel<<<cdiv(NN + 1, B), B, 0, stream>>>(rowptr, bsum, woff, boff, NN);
    p1_kernel<<<cdiv(ET, B), B, 0, stream>>>(src, dst, boff, tmp);
    p2_kernel<<<NBUC, B, 0, stream>>>(rowptr, tmp, woff, ssrc);

    // ---- Layer 1: 128 -> H=4, C=4 (concat 16), ELU ----
    gemm_kernel<128, 16><<<cdiv((long)NN * 16, B), B, 0, stream>>>(x1, W1, hbuf, NN);
    attn_kernel<4, 4><<<cdiv((long)NN * 4, B), B, 0, stream>>>(hbuf, as1, ad1, esrc, edst, NN);
    agg_kernel<4, 4, 4, 4, 4, true><<<cdiv(NN, 16), B, 0, stream>>>(rowptr, ssrc, esrc, edst, hbuf, b1, x2, NN);

    // ---- Layer 2: 16 -> H=8, C=8 (concat 64), ELU ----
    gemm_kernel<16, 64><<<cdiv((long)NN * 64, B), B, 0, stream>>>(x2, W2, hbuf, NN);
    attn_kernel<8, 8><<<cdiv((long)NN * 8, B), B, 0, stream>>>(hbuf, as2, ad2, esrc, edst, NN);
    agg_kernel<8, 8, 16, 4, 1, true><<<cdiv(NN, 4), B, 0, stream>>>(rowptr, ssrc, esrc, edst, hbuf, b2, x3, NN);

    // ---- Layer 3: 64 -> H=1, C=40, no concat, no ELU ----
    gemm_kernel<64, 40><<<cdiv((long)NN * 40, B), B, 0, stream>>>(x3, W3, hbuf, NN);
    attn_kernel<1, 40><<<cdiv((long)NN * 1, B), B, 0, stream>>>(hbuf, as3, ad3, esrc, edst, NN);
    agg_kernel<1, 40, 16, 4, 1, false><<<cdiv(NN, 4), B, 0, stream>>>(rowptr, ssrc, esrc, edst, hbuf, b3, out, NN);
}